// Round 4
// baseline (224.142 us; speedup 1.0000x reference)
//
#include <hip/hip_runtime.h>

#define ROWS_PER_TILE 64
#define THREADS 64
#define ROW_F 85        // floats per row
#define NCLS 80         // classes
#define CONF_THRESH 0.25f

#define TILE_F (ROWS_PER_TILE * ROW_F)   // 5440 floats = 21,760 B LDS
#define TILE_V (TILE_F / 4)              // 1360 float4
#define PER_THREAD 21                    // 64*21 = 1344
#define TAIL_V (TILE_V - PER_THREAD * THREADS)  // 16
#define TILES_PER_BLOCK 4

// Single wave (64 threads) per block, 21,760 B LDS -> 7 blocks/CU. Each block
// processes 4 consecutive 64-row tiles, software-pipelined: while computing
// tile i from LDS, tile i+1's 22 float4 loads are in flight into registers;
// after compute, regs -> LDS. NO __syncthreads anywhere: a barrier's
// vmcnt(0)-drain semantics would serialize the prefetch. Correctness within
// the single wave comes from the in-order per-wave DS pipe (LDS reads of tile
// i are issued, in program order, before LDS writes of tile i+1 to the same
// addresses). LDS row stride 85: t*85 % 32 = t*21 % 32 is a bank permutation
// (21 odd) -> compute-phase reads conflict-free.
__global__ __launch_bounds__(THREADS) void yolo_post_kernel(
    const float* __restrict__ in, float* __restrict__ out, long long nrows) {
  __shared__ float tile[TILE_F];
  float4* dstv = (float4*)tile;
  const int t = threadIdx.x;

  const long long full_tiles = nrows / ROWS_PER_TILE;
  const long long ntiles = (nrows + ROWS_PER_TILE - 1) / ROWS_PER_TILE;
  long long ti = (long long)blockIdx.x * TILES_PER_BLOCK;
  long long ti_end = ti + TILES_PER_BLOCK;
  if (ti_end > ntiles) ti_end = ntiles;
  if (ti >= ti_end) return;
  long long full_end = ti_end < full_tiles ? ti_end : full_tiles;

  float4 v[PER_THREAD];
  float4 extra;

  // ---------------- pipelined path over FULL tiles ----------------
  if (ti < full_end) {
    // prologue: load tile ti into regs, then regs -> LDS
    {
      const float4* __restrict__ src = (const float4*)(in + ti * TILE_F);
#pragma unroll
      for (int k = 0; k < PER_THREAD; ++k) v[k] = src[t + k * THREADS];
      if (t < TAIL_V) extra = src[PER_THREAD * THREADS + t];
    }
#pragma unroll
    for (int k = 0; k < PER_THREAD; ++k) dstv[t + k * THREADS] = v[k];
    if (t < TAIL_V) dstv[PER_THREAD * THREADS + t] = extra;

    while (ti < full_end) {
      const long long nxt = ti + 1;
      const bool have_next = nxt < full_end;
      if (have_next) {
        // prefetch next tile into regs; loads stay in flight during compute
        const float4* __restrict__ src = (const float4*)(in + nxt * TILE_F);
#pragma unroll
        for (int k = 0; k < PER_THREAD; ++k) v[k] = src[t + k * THREADS];
        if (t < TAIL_V) extra = src[PER_THREAD * THREADS + t];
      }

      // ---- compute current tile from LDS ----
      const long long r = ti * ROWS_PER_TILE + t;
      const float* row = tile + t * ROW_F;
      float cx = row[0];
      float cy = row[1];
      float hw = row[2] * 0.5f;
      float hh = row[3] * 0.5f;
      float conf = row[4];
      float best = row[5];
      int bidx = 0;
#pragma unroll
      for (int c = 1; c < NCLS; ++c) {
        float x = row[5 + c];
        bool g = x > best;           // strict > keeps FIRST max (jnp.argmax)
        best = g ? x : best;
        bidx = g ? c : bidx;
      }
      float score = conf * best;
      bool keep = score > CONF_THRESH;
      float2 o01 = keep ? make_float2(cx - hw, cy - hh) : make_float2(0.f, 0.f);
      float2 o23 = keep ? make_float2(cx + hw, cy + hh) : make_float2(0.f, 0.f);
      float2 o45 = keep ? make_float2(score, (float)bidx) : make_float2(0.f, 0.f);
      float2* op = (float2*)(out + r * 6);   // r*24 B, 8 B aligned
      op[0] = o01;
      op[1] = o23;
      op[2] = o45;

      if (have_next) {
        // drain prefetch into LDS (in-order DS pipe: after the reads above)
#pragma unroll
        for (int k = 0; k < PER_THREAD; ++k) dstv[t + k * THREADS] = v[k];
        if (t < TAIL_V) dstv[PER_THREAD * THREADS + t] = extra;
      }
      ti = nxt;
    }
  }

  // ---------------- guarded path for the (at most one) partial tile ----------------
  if (ti < ti_end) {   // ti == full_tiles, partial tile exists
    const long long r = ti * ROWS_PER_TILE + t;
    if (r < nrows) {
      const float* __restrict__ row = in + r * ROW_F;  // direct global, tiny tail
      float cx = row[0];
      float cy = row[1];
      float hw = row[2] * 0.5f;
      float hh = row[3] * 0.5f;
      float conf = row[4];
      float best = row[5];
      int bidx = 0;
      for (int c = 1; c < NCLS; ++c) {
        float x = row[5 + c];
        bool g = x > best;
        best = g ? x : best;
        bidx = g ? c : bidx;
      }
      float score = conf * best;
      bool keep = score > CONF_THRESH;
      float* op = out + r * 6;
      op[0] = keep ? cx - hw : 0.0f;
      op[1] = keep ? cy - hh : 0.0f;
      op[2] = keep ? cx + hw : 0.0f;
      op[3] = keep ? cy + hh : 0.0f;
      op[4] = keep ? score : 0.0f;
      op[5] = keep ? (float)bidx : 0.0f;
    }
  }
}

extern "C" void kernel_launch(void* const* d_in, const int* in_sizes, int n_in,
                              void* d_out, int out_size, void* d_ws, size_t ws_size,
                              hipStream_t stream) {
  const float* in = (const float*)d_in[0];
  float* out = (float*)d_out;
  const long long nrows = (long long)in_sizes[0] / ROW_F;            // 403200
  const long long ntiles = (nrows + ROWS_PER_TILE - 1) / ROWS_PER_TILE;  // 6300
  const int grid = (int)((ntiles + TILES_PER_BLOCK - 1) / TILES_PER_BLOCK);  // 1575
  yolo_post_kernel<<<grid, THREADS, 0, stream>>>(in, out, nrows);
}